// Round 14
// baseline (439.669 us; speedup 1.0000x reference)
//
#include <hip/hip_runtime.h>
#include <stdint.h>

#define N_NODES 50000
#define N_EDGES 1600000
#define IN_DIM  128
#define OUT_DIM 64
#define HEADS   4
#define HO      (HEADS*OUT_DIM)   // 256

typedef __attribute__((ext_vector_type(8))) short short8;            // 8 bf16 (4 VGPR)
typedef __attribute__((ext_vector_type(8))) unsigned short bf16x8;   // 8 bf16 payload
typedef __attribute__((ext_vector_type(4))) float f32x4;             // MFMA C/D

// ---------- helpers ----------
__device__ __forceinline__ float lrelu(float v) {
    return v >= 0.f ? v : 0.01f * v;
}
__device__ __forceinline__ unsigned short f2bf(float f) {          // RNE
    unsigned u = __float_as_uint(f);
    return (unsigned short)((u + 0x7FFFu + ((u >> 16) & 1u)) >> 16);
}
__device__ __forceinline__ float bf2f(unsigned short b) {
    return __uint_as_float(((unsigned)b) << 16);
}

// ---------- kernel 1: W[h][k][o] fp32 -> wt[n=h*64+o][k] bf16 (tiny, 32 blocks) ----------
__global__ __launch_bounds__(256) void k_prep_wt(
    const float* __restrict__ W, unsigned short* __restrict__ wt)
{
    int item = blockIdx.x * 256 + threadIdx.x;   // [0, 8192)
    int n  = item >> 5;                          // 0..255
    int k0 = (item & 31) * 4;                    // 0..124
    int h = n >> 6, o = n & 63;
    const float* wp = &W[((size_t)h * IN_DIM + k0) * OUT_DIM + o];
    ushort4 u;
    u.x = f2bf(wp[0 * OUT_DIM]);
    u.y = f2bf(wp[1 * OUT_DIM]);
    u.z = f2bf(wp[2 * OUT_DIM]);
    u.w = f2bf(wp[3 * OUT_DIM]);
    *(ushort4*)&wt[(size_t)n * IN_DIM + k0] = u;
}

// ---------- kernel 2: [dst hist + rank blocks] // [MFMA gemm blocks, fp32-x staging] ----------
#define HIST_BLOCKS 1024
#define BM 64
#define GEMM_BLOCKS ((N_NODES + BM - 1) / BM)   // 782

__global__ __launch_bounds__(256) void k_gemm_hist(
    const float* __restrict__ x, const unsigned short* __restrict__ wt,
    const float* __restrict__ a, const int* __restrict__ edst,
    int* __restrict__ cnt, int* __restrict__ rank,
    unsigned short* __restrict__ hb, float* __restrict__ s_src, float* __restrict__ s_dst)
{
    extern __shared__ char smem[];               // 16384 (A) + 65536 (B)

    if (blockIdx.x < HIST_BLOCKS) {
        const int stride = HIST_BLOCKS * 256;
        for (int e = blockIdx.x * 256 + threadIdx.x; e < N_EDGES; e += stride)
            rank[e] = atomicAdd(&cnt[edst[e]], 1);   // 50K distinct counters: no same-line pileup
        return;
    }

    char* Alds = smem;
    char* Blds = smem + 16384;

    const int tid  = threadIdx.x;
    const int wave = tid >> 6;
    const int lane = tid & 63;
    const int node0 = (blockIdx.x - HIST_BLOCKS) * BM;

    // ---- stage A: fp32 x -> bf16, swizzled LDS ----
    {
        #pragma unroll
        for (int j = 0; j < 4; ++j) {
            int o    = (j * 256 + tid) * 16;           // LDS byte offset [0,16384)
            int row  = o >> 8;                          // 0..63
            int fcol = (o & 255) >> 1;                  // float col (multiple of 8)
            int node = node0 + row;
            const float* sp = x + (size_t)(node < N_NODES ? node : N_NODES - 1) * IN_DIM + fcol;
            float4 v0 = *(const float4*)sp;
            float4 v1 = *(const float4*)(sp + 4);
            bf16x8 u;
            u[0] = f2bf(v0.x); u[1] = f2bf(v0.y); u[2] = f2bf(v0.z); u[3] = f2bf(v0.w);
            u[4] = f2bf(v1.x); u[5] = f2bf(v1.y); u[6] = f2bf(v1.z); u[7] = f2bf(v1.w);
            int sw = o ^ (((o >> 8) & 7) << 4);
            *(bf16x8*)(Alds + sw) = u;
        }
    }
    // ---- stage B (bf16 wt, linear -> swizzled) ----
    {
        const char* wsrc = (const char*)wt;            // 256 n x 256 B
        #pragma unroll
        for (int j = 0; j < 16; ++j) {
            int o = (j * 256 + tid) * 16;              // [0,65536)
            uint4 v = *(const uint4*)(wsrc + o);
            int sw = o ^ (((o >> 8) & 7) << 4);
            *(uint4*)(Blds + sw) = v;
        }
    }
    __syncthreads();

    const int wr0  = wave * 16;
    const int l15  = lane & 15;
    const int lhi  = lane >> 4;           // 0..3
    const int kxor = (lane & 7) << 4;     // swizzle const for this lane's row/col

    short8 af[4];
    #pragma unroll
    for (int s = 0; s < 4; ++s)
        af[s] = *(const short8*)(Alds + (wr0 + l15) * 256 + ((s * 64 + lhi * 16) ^ kxor));

    f32x4 acc[16];
    #pragma unroll
    for (int nt = 0; nt < 16; ++nt) acc[nt] = (f32x4){0.f, 0.f, 0.f, 0.f};

    #pragma unroll
    for (int nt = 0; nt < 16; ++nt) {
        const char* bbase = Blds + (nt * 16 + l15) * 256;
        #pragma unroll
        for (int s = 0; s < 4; ++s) {
            short8 bf = *(const short8*)(bbase + ((s * 64 + lhi * 16) ^ kxor));
            acc[nt] = __builtin_amdgcn_mfma_f32_16x16x32_bf16(af[s], bf, acc[nt], 0, 0, 0);
        }
    }

    // ---- epilogue 1: hb write. C/D: col=lane&15, row=(lane>>4)*4+r (m89-verified) ----
    #pragma unroll
    for (int nt = 0; nt < 16; ++nt) {
        int col = nt * 16 + l15;
        #pragma unroll
        for (int r = 0; r < 4; ++r) {
            int node = node0 + wr0 + lhi * 4 + r;
            if (node < N_NODES)
                hb[(size_t)node * HO + col] = f2bf(acc[nt][r]);
        }
    }

    // ---- epilogue 2: fused scores from fp32 acc (shuffle-reduce, NO atomics) ----
    #pragma unroll
    for (int h = 0; h < 4; ++h) {
        float avs0 = a[h*128 +  0 + l15], avs1 = a[h*128 + 16 + l15];
        float avs2 = a[h*128 + 32 + l15], avs3 = a[h*128 + 48 + l15];
        float avd0 = a[h*128 + 64 + l15], avd1 = a[h*128 + 80 + l15];
        float avd2 = a[h*128 + 96 + l15], avd3 = a[h*128 + 112 + l15];
        #pragma unroll
        for (int r = 0; r < 4; ++r) {
            float vs = acc[4*h+0][r]*avs0 + acc[4*h+1][r]*avs1
                     + acc[4*h+2][r]*avs2 + acc[4*h+3][r]*avs3;
            float vd = acc[4*h+0][r]*avd0 + acc[4*h+1][r]*avd1
                     + acc[4*h+2][r]*avd2 + acc[4*h+3][r]*avd3;
            #pragma unroll
            for (int m = 8; m >= 1; m >>= 1) {
                vs += __shfl_xor(vs, m);
                vd += __shfl_xor(vd, m);
            }
            int node = node0 + wr0 + lhi * 4 + r;
            if (l15 == 0 && node < N_NODES) {
                s_src[node * HEADS + h] = vs;
                s_dst[node * HEADS + h] = vd;
            }
        }
    }
}

// ---------- kernel 3: block 0 = exclusive scan; block 1 = atomic-free nodemax ----------
__global__ __launch_bounds__(1024) void k_mid(
    const int* __restrict__ cnt, int* __restrict__ row_start,
    const float* __restrict__ s_src, const float* __restrict__ s_dst,
    float* __restrict__ gmax)   // [0..3]=src max per head, [4..7]=dst max per head
{
    if (blockIdx.x == 0) {
        __shared__ int part[1024];
        const int t  = threadIdx.x;
        const int CH = (N_NODES + 1023) / 1024;      // 49
        const int lo = t * CH;
        const int hi = (lo + CH < N_NODES) ? lo + CH : N_NODES;

        int s = 0;
        for (int i = lo; i < hi; ++i) s += cnt[i];
        part[t] = s;
        __syncthreads();

        for (int off = 1; off < 1024; off <<= 1) {
            int v = (t >= off) ? part[t - off] : 0;
            __syncthreads();
            part[t] += v;
            __syncthreads();
        }

        int run = (t == 0) ? 0 : part[t - 1];
        for (int i = lo; i < hi; ++i) {
            row_start[i] = run;
            run += cnt[i];
        }
        if (t == 1023) row_start[N_NODES] = part[1023];
        return;
    }

    // ---- single-block nodemax: zero atomics ----
    __shared__ float red[16][8];
    float4 ms = make_float4(-1e30f, -1e30f, -1e30f, -1e30f);
    float4 md = ms;
    for (int n = threadIdx.x; n < N_NODES; n += 1024) {
        float4 vs = ((const float4*)s_src)[n];
        float4 vd = ((const float4*)s_dst)[n];
        ms.x = fmaxf(ms.x, vs.x); ms.y = fmaxf(ms.y, vs.y);
        ms.z = fmaxf(ms.z, vs.z); ms.w = fmaxf(ms.w, vs.w);
        md.x = fmaxf(md.x, vd.x); md.y = fmaxf(md.y, vd.y);
        md.z = fmaxf(md.z, vd.z); md.w = fmaxf(md.w, vd.w);
    }
    #pragma unroll
    for (int m = 32; m >= 1; m >>= 1) {
        ms.x = fmaxf(ms.x, __shfl_xor(ms.x, m)); ms.y = fmaxf(ms.y, __shfl_xor(ms.y, m));
        ms.z = fmaxf(ms.z, __shfl_xor(ms.z, m)); ms.w = fmaxf(ms.w, __shfl_xor(ms.w, m));
        md.x = fmaxf(md.x, __shfl_xor(md.x, m)); md.y = fmaxf(md.y, __shfl_xor(md.y, m));
        md.z = fmaxf(md.z, __shfl_xor(md.z, m)); md.w = fmaxf(md.w, __shfl_xor(md.w, m));
    }
    const int w = threadIdx.x >> 6;
    if ((threadIdx.x & 63) == 0) {
        red[w][0] = ms.x; red[w][1] = ms.y; red[w][2] = ms.z; red[w][3] = ms.w;
        red[w][4] = md.x; red[w][5] = md.y; red[w][6] = md.z; red[w][7] = md.w;
    }
    __syncthreads();
    if (threadIdx.x < 8) {
        float m = red[0][threadIdx.x];
        #pragma unroll
        for (int k = 1; k < 16; ++k) m = fmaxf(m, red[k][threadIdx.x]);
        gmax[threadIdx.x] = m;
    }
}

// ---------- kernel 4: bucket + per-head {src, alpha.bf16} streams + exp-sum (8 slots) ----------
#define BUCKET_BLOCKS 256
__global__ __launch_bounds__(256) void k_bucket(
    const int* __restrict__ esrc, const int* __restrict__ edst,
    const int* __restrict__ rank, const int* __restrict__ row_start,
    const float* __restrict__ s_src, const float* __restrict__ s_dst,
    const float* __restrict__ gmax,
    uint2* __restrict__ rech, double* __restrict__ gsum)   // rech[4][N_EDGES], gsum[8][4]
{
    const float mx0 = lrelu(gmax[0] + gmax[4]);
    const float mx1 = lrelu(gmax[1] + gmax[5]);
    const float mx2 = lrelu(gmax[2] + gmax[6]);
    const float mx3 = lrelu(gmax[3] + gmax[7]);
    double a0 = 0.0, a1 = 0.0, a2 = 0.0, a3 = 0.0;
    const int stride = gridDim.x * blockDim.x;
    for (int e = blockIdx.x * blockDim.x + threadIdx.x; e < N_EDGES; e += stride) {
        int s = esrc[e], d = edst[e];
        int pos = row_start[d] + rank[e];
        float4 ss = *(const float4*)&s_src[s * HEADS];
        float4 sd = *(const float4*)&s_dst[d * HEADS];
        unsigned b0 = f2bf(__expf(lrelu(ss.x + sd.x) - mx0));
        unsigned b1 = f2bf(__expf(lrelu(ss.y + sd.y) - mx1));
        unsigned b2 = f2bf(__expf(lrelu(ss.z + sd.z) - mx2));
        unsigned b3 = f2bf(__expf(lrelu(ss.w + sd.w) - mx3));
        rech[pos]                       = make_uint2((unsigned)s, b0);
        rech[N_EDGES + pos]             = make_uint2((unsigned)s, b1);
        rech[2 * (size_t)N_EDGES + pos] = make_uint2((unsigned)s, b2);
        rech[3 * (size_t)N_EDGES + pos] = make_uint2((unsigned)s, b3);
        // accumulate the ROUNDED alphas so normalization matches k_agg exactly
        a0 += (double)bf2f((unsigned short)b0);
        a1 += (double)bf2f((unsigned short)b1);
        a2 += (double)bf2f((unsigned short)b2);
        a3 += (double)bf2f((unsigned short)b3);
    }
    #pragma unroll
    for (int m = 32; m >= 1; m >>= 1) {
        a0 += __shfl_xor(a0, m); a1 += __shfl_xor(a1, m);
        a2 += __shfl_xor(a2, m); a3 += __shfl_xor(a3, m);
    }
    __shared__ double part[4][4];
    const int wave = threadIdx.x >> 6;
    if ((threadIdx.x & 63) == 0) {
        part[wave][0] = a0; part[wave][1] = a1; part[wave][2] = a2; part[wave][3] = a3;
    }
    __syncthreads();
    if (threadIdx.x < 4) {
        double t = part[0][threadIdx.x] + part[1][threadIdx.x]
                 + part[2][threadIdx.x] + part[3][threadIdx.x];
        atomicAdd(&gsum[(blockIdx.x & 7) * 4 + threadIdx.x], t);   // 8 slots: /8 line contention
    }
}

// ---------- kernel 5: XCD-sliced gather. slice = blockIdx&7 -> 32-col slice of hb ----------
// Each XCD's blocks gather only a 3.2MB column slice of hb -> L2-resident after warmup.
// Wave = 1 node; 16 edge-quads in flight; butterfly reduce over lane bits 2..5.
__global__ __launch_bounds__(256) void k_agg(
    const int* __restrict__ row_start, const uint2* __restrict__ rech,
    const unsigned short* __restrict__ hb,
    const double* __restrict__ gsum, float* __restrict__ out)
{
    const int slice = blockIdx.x & 7;            // -> XCD (blockIdx % 8 round-robin)
    const int wid   = (blockIdx.x >> 3) * 4 + (threadIdx.x >> 6);
    if (wid >= N_NODES) return;
    const int lane = threadIdx.x & 63;
    const int eq   = lane >> 2;                  // edge-slot within wave: 0..15
    const int cl   = lane & 3;                   // col-quarter within slice
    const int head = slice >> 1;
    const int col  = head * OUT_DIM + (slice & 1) * 32 + cl * 8;   // 8 bf16 per lane

    const int beg = row_start[wid];
    const int end = row_start[wid + 1];
    const uint2* rp = rech + (size_t)head * N_EDGES;

    double gs = 0.0;
    #pragma unroll
    for (int r = 0; r < 8; ++r) gs += gsum[r * 4 + head];
    const float inv = (float)(1.0 / gs);

    float c0=0.f,c1=0.f,c2=0.f,c3=0.f,c4=0.f,c5=0.f,c6=0.f,c7=0.f;

    for (int j = beg + eq; j < end; j += 16) {
        uint2 r = rp[j];                                           // {src, alpha.bf16}
        float p = bf2f((unsigned short)r.y);
        bf16x8 u = *(const bf16x8*)&hb[(size_t)r.x * HO + col];    // L2-resident slice
        c0 = fmaf(p, bf2f(u[0]), c0); c1 = fmaf(p, bf2f(u[1]), c1);
        c2 = fmaf(p, bf2f(u[2]), c2); c3 = fmaf(p, bf2f(u[3]), c3);
        c4 = fmaf(p, bf2f(u[4]), c4); c5 = fmaf(p, bf2f(u[5]), c5);
        c6 = fmaf(p, bf2f(u[6]), c6); c7 = fmaf(p, bf2f(u[7]), c7);
    }

    // reduce across the 16 edge-slots (lane bits 2..5), col-quarter stays fixed
    #pragma unroll
    for (int m = 4; m <= 32; m <<= 1) {
        c0 += __shfl_xor(c0, m); c1 += __shfl_xor(c1, m);
        c2 += __shfl_xor(c2, m); c3 += __shfl_xor(c3, m);
        c4 += __shfl_xor(c4, m); c5 += __shfl_xor(c5, m);
        c6 += __shfl_xor(c6, m); c7 += __shfl_xor(c7, m);
    }

    if (eq == 0) {   // lanes 0..3 write 32B each -> 128B contiguous per node-slice
        float* op = &out[(size_t)wid * HO + col];
        *(float4*)op       = make_float4(c0 * inv, c1 * inv, c2 * inv, c3 * inv);
        *(float4*)(op + 4) = make_float4(c4 * inv, c5 * inv, c6 * inv, c7 * inv);
    }
}

// ---------- launch ----------
extern "C" void kernel_launch(void* const* d_in, const int* in_sizes, int n_in,
                              void* d_out, int out_size, void* d_ws, size_t ws_size,
                              hipStream_t stream)
{
    const float* x    = (const float*)d_in[0];
    const int*   eidx = (const int*)d_in[1];   // jax x64 off: int64 -> int32
    const float* W    = (const float*)d_in[2];
    const float* a    = (const float*)d_in[3];
    float* out = (float*)d_out;

    // workspace layout (gsum|gmax|cnt contiguous for one memset)
    unsigned short* hb = (unsigned short*)d_ws;                      // 12.8M bf16 (25.6 MB)
    unsigned short* wt = hb + (size_t)N_NODES * HO;                  // 32768 bf16
    float*    s_src    = (float*)(wt + (size_t)HO * IN_DIM);         // 200K floats
    float*    s_dst    = s_src + (size_t)N_NODES * HEADS;            // 200K floats
    double*   gsum     = (double*)(s_dst + (size_t)N_NODES * HEADS); // 32 doubles (8 slots x 4)
    float*    gmax     = (float*)(gsum + 32);                        // 8 floats
    int*      cnt      = (int*)(gmax + 8);                           // N_NODES ints
    int*      row_start = cnt + N_NODES;                             // N_NODES+2 ints
    int*      rank     = row_start + (N_NODES + 2);                  // N_EDGES ints
    uint2*    rech     = (uint2*)(rank + N_EDGES);                   // 4*N_EDGES uint2 (51.2 MB)

    const int* esrc = eidx;
    const int* edst = eidx + N_EDGES;

    // one memset: gsum(256B) + gmax(32B) + cnt(200KB)
    hipMemsetAsync(gsum, 0, 32 * sizeof(double) + 8 * sizeof(float) + N_NODES * sizeof(int),
                   stream);

    k_prep_wt<<<32, 256, 0, stream>>>(W, wt);
    k_gemm_hist<<<HIST_BLOCKS + GEMM_BLOCKS, 256, 81920, stream>>>(
        x, wt, a, edst, cnt, rank, hb, s_src, s_dst);
    k_mid<<<2, 1024, 0, stream>>>(cnt, row_start, s_src, s_dst, gmax);
    k_bucket<<<BUCKET_BLOCKS, 256, 0, stream>>>(
        esrc, edst, rank, row_start, s_src, s_dst, gmax, rech, gsum);
    k_agg<<<((N_NODES + 3) / 4) * 8, 256, 0, stream>>>(
        row_start, rech, hb, gsum, out);
}

// Round 15
// 318.181 us; speedup vs baseline: 1.3818x; 1.3818x over previous
//
#include <hip/hip_runtime.h>
#include <stdint.h>

#define N_NODES 50000
#define N_EDGES 1600000
#define IN_DIM  128
#define OUT_DIM 64
#define HEADS   4
#define HO      (HEADS*OUT_DIM)   // 256

typedef __attribute__((ext_vector_type(8))) short short8;            // 8 bf16 (4 VGPR)
typedef __attribute__((ext_vector_type(8))) unsigned short bf16x8;   // 8 bf16 payload
typedef __attribute__((ext_vector_type(4))) float f32x4;             // MFMA C/D

// ---------- helpers ----------
__device__ __forceinline__ float lrelu(float v) {
    return v >= 0.f ? v : 0.01f * v;
}
__device__ __forceinline__ unsigned short f2bf(float f) {          // RNE
    unsigned u = __float_as_uint(f);
    return (unsigned short)((u + 0x7FFFu + ((u >> 16) & 1u)) >> 16);
}
__device__ __forceinline__ float bf2f(unsigned short b) {
    return __uint_as_float(((unsigned)b) << 16);
}

// ---------- kernel 1: W[h][k][o] fp32 -> wt[n=h*64+o][k] bf16 (tiny, 32 blocks) ----------
__global__ __launch_bounds__(256) void k_prep_wt(
    const float* __restrict__ W, unsigned short* __restrict__ wt)
{
    int item = blockIdx.x * 256 + threadIdx.x;   // [0, 8192)
    int n  = item >> 5;                          // 0..255
    int k0 = (item & 31) * 4;                    // 0..124
    int h = n >> 6, o = n & 63;
    const float* wp = &W[((size_t)h * IN_DIM + k0) * OUT_DIM + o];
    ushort4 u;
    u.x = f2bf(wp[0 * OUT_DIM]);
    u.y = f2bf(wp[1 * OUT_DIM]);
    u.z = f2bf(wp[2 * OUT_DIM]);
    u.w = f2bf(wp[3 * OUT_DIM]);
    *(ushort4*)&wt[(size_t)n * IN_DIM + k0] = u;
}

// ---------- kernel 2: [dst hist + rank blocks] // [MFMA gemm blocks] ----------
// Epilogue rewritten (R15): C tile staged through LDS (swizzled) -> coalesced
// 16B stores. Old 2B scattered stores caused 3x write amplification (82MB for
// 26MB of hb) and serialized the kernel on store retirement.
#define HIST_BLOCKS 1024
#define BM 64
#define GEMM_BLOCKS ((N_NODES + BM - 1) / BM)   // 782

__global__ __launch_bounds__(256) void k_gemm_hist(
    const float* __restrict__ x, const unsigned short* __restrict__ wt,
    const float* __restrict__ a, const int* __restrict__ edst,
    int* __restrict__ cnt, int* __restrict__ rank,
    unsigned short* __restrict__ hb, float* __restrict__ s_src, float* __restrict__ s_dst)
{
    extern __shared__ char smem[];               // 16384 (A) + 65536 (B); reused as 32KB C tile

    if (blockIdx.x < HIST_BLOCKS) {
        const int stride = HIST_BLOCKS * 256;
        for (int e = blockIdx.x * 256 + threadIdx.x; e < N_EDGES; e += stride)
            rank[e] = atomicAdd(&cnt[edst[e]], 1);   // 50K distinct counters: no same-line pileup
        return;
    }

    char* Alds = smem;
    char* Blds = smem + 16384;

    const int tid  = threadIdx.x;
    const int wave = tid >> 6;
    const int lane = tid & 63;
    const int node0 = (blockIdx.x - HIST_BLOCKS) * BM;

    // ---- stage A: fp32 x -> bf16, swizzled LDS ----
    {
        #pragma unroll
        for (int j = 0; j < 4; ++j) {
            int o    = (j * 256 + tid) * 16;           // LDS byte offset [0,16384)
            int row  = o >> 8;                          // 0..63
            int fcol = (o & 255) >> 1;                  // float col (multiple of 8)
            int node = node0 + row;
            const float* sp = x + (size_t)(node < N_NODES ? node : N_NODES - 1) * IN_DIM + fcol;
            float4 v0 = *(const float4*)sp;
            float4 v1 = *(const float4*)(sp + 4);
            bf16x8 u;
            u[0] = f2bf(v0.x); u[1] = f2bf(v0.y); u[2] = f2bf(v0.z); u[3] = f2bf(v0.w);
            u[4] = f2bf(v1.x); u[5] = f2bf(v1.y); u[6] = f2bf(v1.z); u[7] = f2bf(v1.w);
            int sw = o ^ (((o >> 8) & 7) << 4);
            *(bf16x8*)(Alds + sw) = u;
        }
    }
    // ---- stage B (bf16 wt, linear -> swizzled) ----
    {
        const char* wsrc = (const char*)wt;            // 256 n x 256 B
        #pragma unroll
        for (int j = 0; j < 16; ++j) {
            int o = (j * 256 + tid) * 16;              // [0,65536)
            uint4 v = *(const uint4*)(wsrc + o);
            int sw = o ^ (((o >> 8) & 7) << 4);
            *(uint4*)(Blds + sw) = v;
        }
    }
    __syncthreads();

    const int wr0  = wave * 16;
    const int l15  = lane & 15;
    const int lhi  = lane >> 4;           // 0..3
    const int kxor = (lane & 7) << 4;     // swizzle const for this lane's row/col

    short8 af[4];
    #pragma unroll
    for (int s = 0; s < 4; ++s)
        af[s] = *(const short8*)(Alds + (wr0 + l15) * 256 + ((s * 64 + lhi * 16) ^ kxor));

    f32x4 acc[16];
    #pragma unroll
    for (int nt = 0; nt < 16; ++nt) acc[nt] = (f32x4){0.f, 0.f, 0.f, 0.f};

    #pragma unroll
    for (int nt = 0; nt < 16; ++nt) {
        const char* bbase = Blds + (nt * 16 + l15) * 256;
        #pragma unroll
        for (int s = 0; s < 4; ++s) {
            short8 bf = *(const short8*)(bbase + ((s * 64 + lhi * 16) ^ kxor));
            acc[nt] = __builtin_amdgcn_mfma_f32_16x16x32_bf16(af[s], bf, acc[nt], 0, 0, 0);
        }
    }

    // ---- epilogue A: fused scores from fp32 acc (shuffle-reduce, NO atomics) ----
    #pragma unroll
    for (int h = 0; h < 4; ++h) {
        float avs0 = a[h*128 +  0 + l15], avs1 = a[h*128 + 16 + l15];
        float avs2 = a[h*128 + 32 + l15], avs3 = a[h*128 + 48 + l15];
        float avd0 = a[h*128 + 64 + l15], avd1 = a[h*128 + 80 + l15];
        float avd2 = a[h*128 + 96 + l15], avd3 = a[h*128 + 112 + l15];
        #pragma unroll
        for (int r = 0; r < 4; ++r) {
            float vs = acc[4*h+0][r]*avs0 + acc[4*h+1][r]*avs1
                     + acc[4*h+2][r]*avs2 + acc[4*h+3][r]*avs3;
            float vd = acc[4*h+0][r]*avd0 + acc[4*h+1][r]*avd1
                     + acc[4*h+2][r]*avd2 + acc[4*h+3][r]*avd3;
            #pragma unroll
            for (int m = 8; m >= 1; m >>= 1) {
                vs += __shfl_xor(vs, m);
                vd += __shfl_xor(vd, m);
            }
            int node = node0 + wr0 + lhi * 4 + r;
            if (l15 == 0 && node < N_NODES) {
                s_src[node * HEADS + h] = vs;
                s_dst[node * HEADS + h] = vd;
            }
        }
    }

    // ---- epilogue B: acc -> swizzled bf16 C tile in LDS -> coalesced 16B stores ----
    __syncthreads();                              // all LDS A/B reads complete; reuse smem
    #pragma unroll
    for (int nt = 0; nt < 16; ++nt) {
        int col = nt * 16 + l15;
        #pragma unroll
        for (int r = 0; r < 4; ++r) {
            int row  = wr0 + lhi * 4 + r;
            int byte = (row * 512 + col * 2) ^ ((row & 7) << 4);
            *(unsigned short*)(smem + byte) = f2bf(acc[nt][r]);
        }
    }
    __syncthreads();
    {
        char* hdst = (char*)hb + (size_t)node0 * 512;
        #pragma unroll
        for (int k = 0; k < 8; ++k) {
            int i    = k * 256 + tid;             // [0,2048) 16B chunks
            int row  = i >> 5;
            int byte = (row * 512 + (i & 31) * 16) ^ ((row & 7) << 4);
            uint4 v  = *(const uint4*)(smem + byte);
            if (node0 + row < N_NODES)
                *(uint4*)(hdst + (size_t)i * 16) = v;   // 1KB contiguous per wave-instr
        }
    }
}

// ---------- kernel 3: block 0 = exclusive scan; block 1 = atomic-free nodemax ----------
__global__ __launch_bounds__(1024) void k_mid(
    const int* __restrict__ cnt, int* __restrict__ row_start,
    const float* __restrict__ s_src, const float* __restrict__ s_dst,
    float* __restrict__ gmax)   // [0..3]=src max per head, [4..7]=dst max per head
{
    if (blockIdx.x == 0) {
        __shared__ int part[1024];
        const int t  = threadIdx.x;
        const int CH = (N_NODES + 1023) / 1024;      // 49
        const int lo = t * CH;
        const int hi = (lo + CH < N_NODES) ? lo + CH : N_NODES;

        int s = 0;
        for (int i = lo; i < hi; ++i) s += cnt[i];
        part[t] = s;
        __syncthreads();

        for (int off = 1; off < 1024; off <<= 1) {
            int v = (t >= off) ? part[t - off] : 0;
            __syncthreads();
            part[t] += v;
            __syncthreads();
        }

        int run = (t == 0) ? 0 : part[t - 1];
        for (int i = lo; i < hi; ++i) {
            row_start[i] = run;
            run += cnt[i];
        }
        if (t == 1023) row_start[N_NODES] = part[1023];
        return;
    }

    // ---- single-block nodemax: zero atomics ----
    __shared__ float red[16][8];
    float4 ms = make_float4(-1e30f, -1e30f, -1e30f, -1e30f);
    float4 md = ms;
    for (int n = threadIdx.x; n < N_NODES; n += 1024) {
        float4 vs = ((const float4*)s_src)[n];
        float4 vd = ((const float4*)s_dst)[n];
        ms.x = fmaxf(ms.x, vs.x); ms.y = fmaxf(ms.y, vs.y);
        ms.z = fmaxf(ms.z, vs.z); ms.w = fmaxf(ms.w, vs.w);
        md.x = fmaxf(md.x, vd.x); md.y = fmaxf(md.y, vd.y);
        md.z = fmaxf(md.z, vd.z); md.w = fmaxf(md.w, vd.w);
    }
    #pragma unroll
    for (int m = 32; m >= 1; m >>= 1) {
        ms.x = fmaxf(ms.x, __shfl_xor(ms.x, m)); ms.y = fmaxf(ms.y, __shfl_xor(ms.y, m));
        ms.z = fmaxf(ms.z, __shfl_xor(ms.z, m)); ms.w = fmaxf(ms.w, __shfl_xor(ms.w, m));
        md.x = fmaxf(md.x, __shfl_xor(md.x, m)); md.y = fmaxf(md.y, __shfl_xor(md.y, m));
        md.z = fmaxf(md.z, __shfl_xor(md.z, m)); md.w = fmaxf(md.w, __shfl_xor(md.w, m));
    }
    const int w = threadIdx.x >> 6;
    if ((threadIdx.x & 63) == 0) {
        red[w][0] = ms.x; red[w][1] = ms.y; red[w][2] = ms.z; red[w][3] = ms.w;
        red[w][4] = md.x; red[w][5] = md.y; red[w][6] = md.z; red[w][7] = md.w;
    }
    __syncthreads();
    if (threadIdx.x < 8) {
        float m = red[0][threadIdx.x];
        #pragma unroll
        for (int k = 1; k < 16; ++k) m = fmaxf(m, red[k][threadIdx.x]);
        gmax[threadIdx.x] = m;
    }
}

// ---------- kernel 4: bucket + pack {src, alpha[4].bf16} + exp-sum (8 replicated slots) ----------
#define BUCKET_BLOCKS 256
__global__ __launch_bounds__(256) void k_bucket(
    const int* __restrict__ esrc, const int* __restrict__ edst,
    const int* __restrict__ rank, const int* __restrict__ row_start,
    const float* __restrict__ s_src, const float* __restrict__ s_dst,
    const float* __restrict__ gmax,
    unsigned* __restrict__ rec, double* __restrict__ gsum)   // gsum[8][4]
{
    const float mx0 = lrelu(gmax[0] + gmax[4]);
    const float mx1 = lrelu(gmax[1] + gmax[5]);
    const float mx2 = lrelu(gmax[2] + gmax[6]);
    const float mx3 = lrelu(gmax[3] + gmax[7]);
    double a0 = 0.0, a1 = 0.0, a2 = 0.0, a3 = 0.0;
    const int stride = gridDim.x * blockDim.x;
    for (int e = blockIdx.x * blockDim.x + threadIdx.x; e < N_EDGES; e += stride) {
        int s = esrc[e], d = edst[e];
        int pos = row_start[d] + rank[e];
        float4 ss = *(const float4*)&s_src[s * HEADS];
        float4 sd = *(const float4*)&s_dst[d * HEADS];
        unsigned b0 = f2bf(__expf(lrelu(ss.x + sd.x) - mx0));
        unsigned b1 = f2bf(__expf(lrelu(ss.y + sd.y) - mx1));
        unsigned b2 = f2bf(__expf(lrelu(ss.z + sd.z) - mx2));
        unsigned b3 = f2bf(__expf(lrelu(ss.w + sd.w) - mx3));
        rec[(size_t)pos * 3 + 0] = (unsigned)s;
        rec[(size_t)pos * 3 + 1] = b0 | (b1 << 16);
        rec[(size_t)pos * 3 + 2] = b2 | (b3 << 16);
        // accumulate the ROUNDED alphas so normalization matches k_agg exactly
        a0 += (double)bf2f((unsigned short)b0);
        a1 += (double)bf2f((unsigned short)b1);
        a2 += (double)bf2f((unsigned short)b2);
        a3 += (double)bf2f((unsigned short)b3);
    }
    #pragma unroll
    for (int m = 32; m >= 1; m >>= 1) {
        a0 += __shfl_xor(a0, m); a1 += __shfl_xor(a1, m);
        a2 += __shfl_xor(a2, m); a3 += __shfl_xor(a3, m);
    }
    __shared__ double part[4][4];
    const int wave = threadIdx.x >> 6;
    if ((threadIdx.x & 63) == 0) {
        part[wave][0] = a0; part[wave][1] = a1; part[wave][2] = a2; part[wave][3] = a3;
    }
    __syncthreads();
    if (threadIdx.x < 4) {
        double t = part[0][threadIdx.x] + part[1][threadIdx.x]
                 + part[2][threadIdx.x] + part[3][threadIdx.x];
        atomicAdd(&gsum[(blockIdx.x & 7) * 4 + threadIdx.x], t);   // 8 slots: /8 line contention
    }
}

// ---------- kernel 5: one wave per dst node; 2 edge-streams/wave, unroll 4 (R12-proven) ----------
__global__ __launch_bounds__(256) void k_agg(
    const int* __restrict__ row_start, const unsigned* __restrict__ rec,
    const unsigned short* __restrict__ hb,
    const double* __restrict__ gsum, float* __restrict__ out)
{
    const int wid = (int)((blockIdx.x * 256u + threadIdx.x) >> 6);   // node id
    if (wid >= N_NODES) return;
    const int lane = threadIdx.x & 63;
    const int half = lane >> 5;           // edge-stream selector
    const int l32  = lane & 31;
    const int head = l32 >> 3;            // 0..3
    const int og   = (l32 & 7) * 8;       // 0,8,...,56
    const int hoff = head * OUT_DIM + og;

    const int beg = row_start[wid];
    const int end = row_start[wid + 1];
    double gs = 0.0;
    #pragma unroll
    for (int r = 0; r < 8; ++r) gs += gsum[r * 4 + head];
    const float inv = (float)(1.0 / gs);

    float c0=0.f,c1=0.f,c2=0.f,c3=0.f,c4=0.f,c5=0.f,c6=0.f,c7=0.f;

    #define EDGE(rc)                                                            \
        {                                                                       \
            unsigned aw = (head & 2) ? (rc).z : (rc).y;                         \
            float p = bf2f((unsigned short)((head & 1) ? (aw >> 16)             \
                                                       : (aw & 0xFFFFu)));      \
            bf16x8 u = *(const bf16x8*)&hb[(size_t)(rc).x * HO + hoff];         \
            c0 = fmaf(p, bf2f(u[0]), c0); c1 = fmaf(p, bf2f(u[1]), c1);         \
            c2 = fmaf(p, bf2f(u[2]), c2); c3 = fmaf(p, bf2f(u[3]), c3);         \
            c4 = fmaf(p, bf2f(u[4]), c4); c5 = fmaf(p, bf2f(u[5]), c5);         \
            c6 = fmaf(p, bf2f(u[6]), c6); c7 = fmaf(p, bf2f(u[7]), c7);         \
        }

    int j = beg + half;                   // this half-wave's edge stream: j, j+2, ...
    for (; j + 6 < end; j += 8) {         // 4 edges per half per iter (8/wave)
        uint3 rA = *(const uint3*)&rec[(size_t)j * 3];
        uint3 rB = *(const uint3*)&rec[(size_t)(j + 2) * 3];
        uint3 rC = *(const uint3*)&rec[(size_t)(j + 4) * 3];
        uint3 rD = *(const uint3*)&rec[(size_t)(j + 6) * 3];
        EDGE(rA); EDGE(rB); EDGE(rC); EDGE(rD);
    }
    for (; j < end; j += 2) {
        uint3 rA = *(const uint3*)&rec[(size_t)j * 3];
        EDGE(rA);
    }
    #undef EDGE

    // combine the two half-wave partial sums
    c0 += __shfl_xor(c0, 32); c1 += __shfl_xor(c1, 32);
    c2 += __shfl_xor(c2, 32); c3 += __shfl_xor(c3, 32);
    c4 += __shfl_xor(c4, 32); c5 += __shfl_xor(c5, 32);
    c6 += __shfl_xor(c6, 32); c7 += __shfl_xor(c7, 32);

    float4 v = half ? make_float4(c4 * inv, c5 * inv, c6 * inv, c7 * inv)
                    : make_float4(c0 * inv, c1 * inv, c2 * inv, c3 * inv);
    *(float4*)&out[(size_t)wid * HO + hoff + half * 4] = v;
}

// ---------- launch ----------
extern "C" void kernel_launch(void* const* d_in, const int* in_sizes, int n_in,
                              void* d_out, int out_size, void* d_ws, size_t ws_size,
                              hipStream_t stream)
{
    const float* x    = (const float*)d_in[0];
    const int*   eidx = (const int*)d_in[1];   // jax x64 off: int64 -> int32
    const float* W    = (const float*)d_in[2];
    const float* a    = (const float*)d_in[3];
    float* out = (float*)d_out;

    // workspace layout (gsum|gmax|cnt contiguous for one memset)
    unsigned short* hb = (unsigned short*)d_ws;                      // 12.8M bf16 (25.6 MB)
    unsigned short* wt = hb + (size_t)N_NODES * HO;                  // 32768 bf16
    float*    s_src    = (float*)(wt + (size_t)HO * IN_DIM);         // 200K floats
    float*    s_dst    = s_src + (size_t)N_NODES * HEADS;            // 200K floats
    double*   gsum     = (double*)(s_dst + (size_t)N_NODES * HEADS); // 32 doubles (8 slots x 4)
    float*    gmax     = (float*)(gsum + 32);                        // 8 floats
    int*      cnt      = (int*)(gmax + 8);                           // N_NODES ints
    int*      row_start = cnt + N_NODES;                             // N_NODES+2 ints
    int*      rank     = row_start + (N_NODES + 2);                  // N_EDGES ints
    unsigned* rec      = (unsigned*)(rank + N_EDGES);                // 3*N_EDGES uints (12B/edge)

    const int* esrc = eidx;
    const int* edst = eidx + N_EDGES;

    // one memset: gsum(256B) + gmax(32B) + cnt(200KB)
    hipMemsetAsync(gsum, 0, 32 * sizeof(double) + 8 * sizeof(float) + N_NODES * sizeof(int),
                   stream);

    k_prep_wt<<<32, 256, 0, stream>>>(W, wt);
    k_gemm_hist<<<HIST_BLOCKS + GEMM_BLOCKS, 256, 81920, stream>>>(
        x, wt, a, edst, cnt, rank, hb, s_src, s_dst);
    k_mid<<<2, 1024, 0, stream>>>(cnt, row_start, s_src, s_dst, gmax);
    k_bucket<<<BUCKET_BLOCKS, 256, 0, stream>>>(
        esrc, edst, rank, row_start, s_src, s_dst, gmax, rec, gsum);
    k_agg<<<(N_NODES * 64 + 255) / 256, 256, 0, stream>>>(
        row_start, rec, hb, gsum, out);
}